// Round 11
// baseline (131.057 us; speedup 1.0000x reference)
//
#include <hip/hip_runtime.h>

// FAVOR+ causal linear attention, fp32 I/O, bf16 MFMA chunked-GEMM form.
// B=2, L=4096, H=8, D=64, M=128, chunks C=64 x T=64.
// R11 = R10 + VGPR-headroom exploitation: grid 1024 pins 4 blocks/CU, so any
// VGPR count <=128 has identical occupancy. __launch_bounds__(256,4) raises
// the compiler budget from its chosen 88 to 128; all 16 P-frags preloaded
// into registers BEFORE the 48-MFMA feature chain (they were loaded in-loop
// at ~200cy L3 latency each). k2 reverted to R6's proven 520x64 bf16x4.
//   k0: P fp32 -> bf16 once.
//   k1: features (Qf swapped -> regs+global; Kf both orientations packed);
//       cs = (V^T Kf, colsum Kf); S swapped (in-lane rowsum); num2 -> n2.
//   k2: exclusive bf16 prefix; 520 x 64, bf16x4, full prefetch.
//   k3: num1 = Qf*KVpre + combine; cs LDS-staged once; Qf from ws (hot).

#define B_ 2
#define L_ 4096
#define H_ 8
#define D_ 64
#define M_ 128
#define BH_ 16
#define HD_ 512
#define LHD_ (L_*HD_)
#define C_ 64
#define T_ 64
#define RATIO 0.08838834764831845f
#define EPS 1e-3f

#define REC_CS 8320                    // shorts per cs record: 64*128 KVt + 128 ks
#define REC_F  8192                    // shorts per Qf record: 64*128
#define QF_OFF 8519680                 // shorts: 16*64*8320
#define N2_OFF 16908288                // shorts: QF_OFF + 16*64*8192 (f32 region)
#define RS_OFF 25296896                // shorts (f32 region)
#define P_OFF  25427968                // shorts; P bf16 [m][d]

// XOR-swizzles (bank-conflict-free; XOR by multiples of 8 shorts preserves
// 8B alignment for bf16x4 and 16B for bf16x8 at col%8==0):
#define SWZ64(r,c)  ((r)*64  + ((c) ^ (((r)&7)*8)))
#define SWZ128(r,c) ((r)*128 + ((c) ^ (((r)&15)*8)))

typedef __attribute__((ext_vector_type(8))) short bf16x8;
typedef __attribute__((ext_vector_type(4))) short bf16x4;
typedef __attribute__((ext_vector_type(4))) float f32x4;

__device__ __forceinline__ short f2bf(float f) {
  union { float f; unsigned u; } x; x.f = f;
  unsigned r = (x.u + 0x7fffu + ((x.u >> 16) & 1u)) >> 16;
  return (short)r;
}
__device__ __forceinline__ float bf2f(short s) {
  union { unsigned u; float f; } x; x.u = ((unsigned)(unsigned short)s) << 16;
  return x.f;
}
__device__ __forceinline__ bf16x8 cvt8(float4 a, float4 b) {
  union { bf16x8 v; short s[8]; } u;
  u.s[0]=f2bf(a.x); u.s[1]=f2bf(a.y); u.s[2]=f2bf(a.z); u.s[3]=f2bf(a.w);
  u.s[4]=f2bf(b.x); u.s[5]=f2bf(b.y); u.s[6]=f2bf(b.z); u.s[7]=f2bf(b.w);
  return u.v;
}
#define MFMA(a,b,c) __builtin_amdgcn_mfma_f32_16x16x32_bf16((a),(b),(c),0,0,0)

// ---------------- k0: P -> bf16 once ----------------------------------------
__global__ __launch_bounds__(256) void k0(
    const float* __restrict__ P, unsigned short* __restrict__ ws)
{
  const int i = (blockIdx.x*256 + threadIdx.x)*4;   // 8 blocks * 256 * 4 = 8192
  float4 p4 = *(const float4*)(P + i);
  union { bf16x4 v; short s[4]; } u;
  u.s[0]=f2bf(p4.x); u.s[1]=f2bf(p4.y); u.s[2]=f2bf(p4.z); u.s[3]=f2bf(p4.w);
  *(bf16x4*)(ws + P_OFF + i) = u.v;
}

// ---------------- k1: all intra-chunk work (40KB LDS, 4 blocks/CU) ----------
__global__ __launch_bounds__(256, 4) void k1(
    const float* __restrict__ qq, const float* __restrict__ kk,
    const float* __restrict__ vv, unsigned short* __restrict__ ws)
{
  __shared__ short Vt[64*64];        // [d][t], SWZ64 (8KB)
  __shared__ short Kft[128*64];      // [m][t], SWZ64 (16KB); rows 0-63 -> Sm
  __shared__ short KfTM[64*128];     // [t][m], SWZ128 (16KB)

  const int tid = threadIdx.x, bid = blockIdx.x;
  const int bh = bid >> 6, c = bid & 63;
  const int b = bh >> 3, h = bh & 7;
  const int lane = tid & 63, w = tid >> 6, quad = lane >> 4, l15 = lane & 15;
  const size_t gbase = (size_t)b*LHD_ + (size_t)h*D_;
  const int t0 = c*T_;
  const int trow = 16*w + l15;
  const unsigned short* Pb = ws + P_OFF;

  // issue q/k row loads first (latency overlaps Vt staging)
  const float* qrow = qq + gbase + (size_t)(t0 + trow)*HD_;
  const float* krow = kk + gbase + (size_t)(t0 + trow)*HD_;
  float4 q4a = *(const float4*)(qrow + quad*8);
  float4 q4b = *(const float4*)(qrow + quad*8 + 4);
  float4 q4c = *(const float4*)(qrow + 32 + quad*8);
  float4 q4d = *(const float4*)(qrow + 32 + quad*8 + 4);
  float4 k4a = *(const float4*)(krow + quad*8);
  float4 k4b = *(const float4*)(krow + quad*8 + 4);
  float4 k4c = *(const float4*)(krow + 32 + quad*8);
  float4 k4d = *(const float4*)(krow + 32 + quad*8 + 4);

  // preload ALL P frags (64 VGPRs) — free under the 4-block grid pin;
  // removes in-loop L3 latency from the 48-MFMA feature chain
  bf16x8 apre[16];
  #pragma unroll
  for (int ct = 0; ct < 8; ++ct) {
    apre[2*ct]   = *(const bf16x8*)(Pb + (ct*16 + l15)*64 + quad*8);
    apre[2*ct+1] = *(const bf16x8*)(Pb + (ct*16 + l15)*64 + 32 + quad*8);
  }

  // stage Vt[d][t]: 4x4 (t,d) tile per thread, packed bf16x4 writes
  {
    const int d4 = (tid & 15)*4, t4 = (tid >> 4)*4;
    const float* vb = vv + gbase + (size_t)(t0 + t4)*HD_ + d4;
    float4 va0 = *(const float4*)(vb);
    float4 va1 = *(const float4*)(vb + HD_);
    float4 va2 = *(const float4*)(vb + 2*HD_);
    float4 va3 = *(const float4*)(vb + 3*HD_);
    const float* p0 = (const float*)&va0;
    const float* p1 = (const float*)&va1;
    const float* p2 = (const float*)&va2;
    const float* p3 = (const float*)&va3;
    #pragma unroll
    for (int r = 0; r < 4; ++r) {
      union { bf16x4 v; short s[4]; } pv;
      pv.s[0] = f2bf(p0[r]); pv.s[1] = f2bf(p1[r]);
      pv.s[2] = f2bf(p2[r]); pv.s[3] = f2bf(p3[r]);
      *(bf16x4*)&Vt[SWZ64(d4 + r, t4)] = pv.v;
    }
  }

  bf16x8 bq0 = cvt8(q4a, q4b), bq1 = cvt8(q4c, q4d);
  bf16x8 bk0 = cvt8(k4a, k4b), bk1 = cvt8(k4c, k4d);

  unsigned short* qfb = ws + QF_OFF + (size_t)(bh*C_+c)*REC_F;
  unsigned short* csb = ws + (size_t)(bh*C_+c)*REC_CS;

  // features. Swapped D[m][t] (A=P,B=x): lane holds t=trow, m=16ct+4quad+reg
  //   -> Qf regs + global, KfTM packed.
  // Normal D[t][m] (A=k,B=P): lane holds t=16w+4quad+reg, m=l15+16ct
  //   -> Kft packed. Swap of MFMA args transposes D, values bit-identical.
  bf16x4 qreg[8];
  #pragma unroll
  for (int ct = 0; ct < 8; ++ct) {
    bf16x8 ap0 = apre[2*ct], ap1 = apre[2*ct+1];
    f32x4 qa = {0.f,0.f,0.f,0.f}, kas = {0.f,0.f,0.f,0.f}, kan = {0.f,0.f,0.f,0.f};
    qa  = MFMA(ap0,bq0,qa);  qa  = MFMA(ap1,bq1,qa);
    kas = MFMA(ap0,bk0,kas); kas = MFMA(ap1,bk1,kas);
    kan = MFMA(bk0,ap0,kan); kan = MFMA(bk1,ap1,kan);
    union { bf16x4 v; short s[4]; } pq, pks, pkn;
    #pragma unroll
    for (int reg = 0; reg < 4; ++reg) {
      pq.s[reg]  = f2bf(fmaxf(qa[reg] *RATIO, 0.f) + EPS);
      pks.s[reg] = f2bf(fmaxf(kas[reg]*RATIO, 0.f) + EPS);
      pkn.s[reg] = f2bf(fmaxf(kan[reg]*RATIO, 0.f) + EPS);
    }
    qreg[ct] = pq.v;
    *(bf16x4*)(qfb + trow*128 + 16*ct + 4*quad) = pq.v;
    *(bf16x4*)&KfTM[SWZ128(trow, 16*ct + 4*quad)] = pks.v;
    *(bf16x4*)&Kft[SWZ64(l15 + 16*ct, 16*w + 4*quad)] = pkn.v;
  }

  // Qf B-frags via in-wave 64-bit shuffles:
  // qfr[ks2] = Qf[trow][32ks2+8quad .. +7]
  bf16x8 qfr[4];
  {
    const int src_lo = (2*(quad & 1))*16 + l15;
    #pragma unroll
    for (int ks2 = 0; ks2 < 4; ++ks2) {
      union { bf16x4 v; long long l; } a0, a1;
      a0.v = qreg[2*ks2]; a1.v = qreg[2*ks2+1];
      long long loA = __shfl(a0.l, src_lo, 64);
      long long hiA = __shfl(a0.l, src_lo + 16, 64);
      long long loB = __shfl(a1.l, src_lo, 64);
      long long hiB = __shfl(a1.l, src_lo + 16, 64);
      union { bf16x8 v8; long long l[2]; } r;
      r.l[0] = (quad < 2) ? loA : loB;
      r.l[1] = (quad < 2) ? hiA : hiB;
      qfr[ks2] = r.v8;
    }
  }
  __syncthreads();  // sync1: Vt, Kft, KfTM complete

  // ks[m] = sum_t Kf[t][m] (row-sum of Kft)
  if (tid < 128) {
    float s = 0.f;
    #pragma unroll
    for (int i = 0; i < 8; ++i) {
      bf16x8 r = *(const bf16x8*)&Kft[SWZ64(tid, 8*i)];
      #pragma unroll
      for (int j = 0; j < 8; ++j) s += bf2f(r[j]);
    }
    csb[64*128 + tid] = (unsigned short)f2bf(s);
  }

  // KV^T: cs[d][m] = sum_t Kf[t][m] V[t][d]; D[m][d], packed 8B stores
  {
    bf16x8 av0 = *(const bf16x8*)&Vt[SWZ64(trow, 8*quad)];
    bf16x8 av1 = *(const bf16x8*)&Vt[SWZ64(trow, 32 + 8*quad)];
    #pragma unroll
    for (int mt = 0; mt < 8; ++mt) {
      bf16x8 b0 = *(const bf16x8*)&Kft[SWZ64(16*mt + l15, 8*quad)];
      bf16x8 b1 = *(const bf16x8*)&Kft[SWZ64(16*mt + l15, 32 + 8*quad)];
      f32x4 acc = {0.f,0.f,0.f,0.f};
      acc = MFMA(b0, av0, acc);
      acc = MFMA(b1, av1, acc);
      union { bf16x4 v; short s[4]; } pc;
      #pragma unroll
      for (int reg = 0; reg < 4; ++reg) pc.s[reg] = f2bf(acc[reg]);
      *(bf16x4*)(csb + trow*128 + 16*mt + 4*quad) = pc.v;
    }
  }

  // S = mask(Qf Kf^T), SWAPPED: D[j][t], A=KfTM rows j, B=qfr.
  // Lane (quad,l15), reg: j = 16jt+4quad+reg, t = trow (own row).
  f32x4 sacc[4];
  #pragma unroll
  for (int jt = 0; jt < 4; ++jt) { f32x4 z = {0.f,0.f,0.f,0.f}; sacc[jt] = z; }
  #pragma unroll
  for (int ks2 = 0; ks2 < 4; ++ks2) {
    #pragma unroll
    for (int jt = 0; jt < 4; ++jt) {
      bf16x8 bb = *(const bf16x8*)&KfTM[SWZ128(16*jt + l15, 32*ks2 + 8*quad)];
      sacc[jt] = MFMA(bb, qfr[ks2], sacc[jt]);
    }
  }
  __syncthreads();  // sync2: Kft/KfTM reads done -> Kft rows 0-63 reusable

  // mask + in-lane rowsum + packed Sm writes (reuse Kft; same-wave rows only)
  short* Sm = Kft;
  float rsl = 0.f;
  #pragma unroll
  for (int jt = 0; jt < 4; ++jt) {
    union { bf16x4 v; short s[4]; } ps;
    #pragma unroll
    for (int reg = 0; reg < 4; ++reg) {
      int j = 16*jt + 4*quad + reg;
      float val = (j <= trow) ? sacc[jt][reg] : 0.f;
      rsl += val;
      ps.s[reg] = f2bf(val);
    }
    *(bf16x4*)&Sm[SWZ64(trow, 16*jt + 4*quad)] = ps.v;
  }
  // full rowsum for row trow: reduce the 4 quads (j mod 16 partition)
  rsl += __shfl_xor(rsl, 16);
  rsl += __shfl_xor(rsl, 32);
  float* rsg = (float*)(ws + RS_OFF);
  if (quad == 0) rsg[bh*L_ + t0 + trow] = rsl;

  // num2[t][d] = S V as D[d][t]: A=Vt rows d, B=Sm rows t (same-wave)
  float* n2 = (float*)(ws + N2_OFF);
  f32x4 nacc[4];
  #pragma unroll
  for (int ct = 0; ct < 4; ++ct) { f32x4 z = {0.f,0.f,0.f,0.f}; nacc[ct] = z; }
  #pragma unroll
  for (int kss = 0; kss < 2; ++kss) {
    bf16x8 sb = *(const bf16x8*)&Sm[SWZ64(trow, 32*kss + 8*quad)];
    #pragma unroll
    for (int ct = 0; ct < 4; ++ct) {
      bf16x8 a = *(const bf16x8*)&Vt[SWZ64(16*ct + l15, 32*kss + 8*quad)];
      nacc[ct] = MFMA(a, sb, nacc[ct]);
    }
  }
  const int tg = t0 + trow;
  #pragma unroll
  for (int ct = 0; ct < 4; ++ct) {
    float4 o;
    o.x = nacc[ct][0]; o.y = nacc[ct][1]; o.z = nacc[ct][2]; o.w = nacc[ct][3];
    *(float4*)(n2 + gbase + (size_t)tg*HD_ + 16*ct + 4*quad) = o;
  }
}

// ---------------- k2: bf16 exclusive prefix, 520x64, bf16x4 prefetch --------
__global__ __launch_bounds__(64) void k2(unsigned short* __restrict__ ws)
{
  const int gid = blockIdx.x*64 + threadIdx.x;   // 520*64 = 33280 = 16*2080
  const int bh = gid / 2080, e = (gid % 2080)*4;
  unsigned short* base = ws + (size_t)bh*C_*REC_CS + e;
  bf16x4 v[64];
  #pragma unroll
  for (int c2 = 0; c2 < 64; ++c2) v[c2] = *(const bf16x4*)(base + (size_t)c2*REC_CS);
  float run[4] = {0.f,0.f,0.f,0.f};
  #pragma unroll
  for (int c2 = 0; c2 < 64; ++c2) {
    union { bf16x4 v; short s[4]; } wv;
    #pragma unroll
    for (int j = 0; j < 4; ++j) { wv.s[j] = f2bf(run[j]); run[j] += bf2f(v[c2][j]); }
    *(bf16x4*)(base + (size_t)c2*REC_CS) = wv.v;
  }
}

// ---------------- k3: num1 + combine; cs LDS-staged once --------------------
__global__ __launch_bounds__(256, 4) void k3(
    const unsigned short* __restrict__ ws, float* __restrict__ out)
{
  __shared__ short csL[64*128];     // [d][m], SWZ128
  __shared__ float ks_lds[128];

  const int tid = threadIdx.x, bid = blockIdx.x;
  const int bh = bid >> 6, c = bid & 63;
  const int b = bh >> 3, h = bh & 7;
  const int lane = tid & 63, w = tid >> 6, quad = lane >> 4, l15 = lane & 15;
  const size_t gbase = (size_t)b*LHD_ + (size_t)h*D_;
  const int t0 = c*T_;
  const unsigned short* csb = ws + (size_t)(bh*C_+c)*REC_CS;
  const unsigned short* qfb = ws + QF_OFF + (size_t)(bh*C_+c)*REC_F;
  const float* n2 = (const float*)(ws + N2_OFF);
  const float* rsg = (const float*)(ws + RS_OFF);
  const int trow = 16*w + l15;
  const int tg = t0 + trow;

  // stage cs[d][m] (coalesced 16B reads), ks as f32
  for (int i = tid; i < 1024; i += 256) {
    int row = i >> 4, cb = (i & 15)*8;
    *(bf16x8*)&csL[SWZ128(row, cb)] = *(const bf16x8*)(csb + i*8);
  }
  if (tid < 128) ks_lds[tid] = bf2f((short)csb[64*128 + tid]);

  // hoisted global loads: n2, rs, Qf frags (all workspace -> L2/L3-hot)
  float4 nv[4];
  #pragma unroll
  for (int ct = 0; ct < 4; ++ct)
    nv[ct] = *(const float4*)(n2 + gbase + (size_t)tg*HD_ + 16*ct + 4*quad);
  float rsv = rsg[bh*L_ + tg];
  bf16x8 qfB[4];
  #pragma unroll
  for (int ks2 = 0; ks2 < 4; ++ks2)
    qfB[ks2] = *(const bf16x8*)(qfb + trow*128 + ks2*32 + quad*8);

  __syncthreads();

  // den1 = Qf . ks_prefix (per-lane partial over 32 m, reduce across quads)
  float dp = 0.f;
  #pragma unroll
  for (int ks2 = 0; ks2 < 4; ++ks2)
    #pragma unroll
    for (int j = 0; j < 8; ++j) dp += bf2f(qfB[ks2][j]) * ks_lds[ks2*32 + quad*8 + j];
  dp += __shfl_xor(dp, 16);
  dp += __shfl_xor(dp, 32);
  float inv = 1.f / (dp + rsv);

  // num1 = Qf * KVpre as D[d][t]: A=csL rows d, B=Qf rows t
  f32x4 nacc[4];
  #pragma unroll
  for (int ct = 0; ct < 4; ++ct) { f32x4 z = {0.f,0.f,0.f,0.f}; nacc[ct] = z; }
  #pragma unroll
  for (int ks2 = 0; ks2 < 4; ++ks2) {
    #pragma unroll
    for (int ct = 0; ct < 4; ++ct) {
      bf16x8 a = *(const bf16x8*)&csL[SWZ128(16*ct + l15, 32*ks2 + 8*quad)];
      nacc[ct] = MFMA(a, qfB[ks2], nacc[ct]);
    }
  }
  #pragma unroll
  for (int ct = 0; ct < 4; ++ct) {
    float4 o;
    o.x = (nacc[ct][0] + nv[ct].x) * inv;
    o.y = (nacc[ct][1] + nv[ct].y) * inv;
    o.z = (nacc[ct][2] + nv[ct].z) * inv;
    o.w = (nacc[ct][3] + nv[ct].w) * inv;
    *(float4*)(out + gbase + (size_t)tg*HD_ + 16*ct + 4*quad) = o;
  }
}

extern "C" void kernel_launch(void* const* d_in, const int* in_sizes, int n_in,
                              void* d_out, int out_size, void* d_ws, size_t ws_size,
                              hipStream_t stream) {
  const float* q = (const float*)d_in[0];
  const float* k = (const float*)d_in[1];
  const float* v = (const float*)d_in[2];
  const float* P = (const float*)d_in[3];
  float* out = (float*)d_out;
  unsigned short* ws = (unsigned short*)d_ws;  // needs ~50.9 MB

  k0<<<dim3(8),      dim3(256), 0, stream>>>(P, ws);
  k1<<<dim3(BH_*C_), dim3(256), 0, stream>>>(q, k, v, ws);
  k2<<<dim3(520),    dim3(64),  0, stream>>>(ws);
  k3<<<dim3(BH_*C_), dim3(256), 0, stream>>>(ws, out);
}

// Round 12
// 126.917 us; speedup vs baseline: 1.0326x; 1.0326x over previous
//
#include <hip/hip_runtime.h>

// FAVOR+ causal linear attention, fp32 I/O, bf16 MFMA chunked-GEMM form.
// B=2, L=4096, H=8, D=64, M=128, chunks C=64 x T=64.
// R12 = revert to R6 EXACT (best measured: 126.5us). R9-R11's individually
// "neutral" additions drifted cumulatively to -4.6us; reverted wholesale.
//   k0: P fp32 -> bf16 once.
//   k1: features Qf,Kf; cs = (V^T Kf, colsum Kf); S = mask(Qf Kf^T);
//       num2 = S V -> n2 (f32); rs = rowsum(S).
//       Qf A-frags via in-wave 64-bit shuffles; Sm reuses Kft after sync2.
//       40KB LDS -> 4 blocks/CU; grid 1024 = ONE residency round (R6 fix).
//   k2: exclusive bf16 prefix; 520 blocks x 64 thr, bf16x4 full prefetch.
//   k3: num1 = Qf*KVpre + combine; cs LDS-staged once; Qf from ws (hot).

#define B_ 2
#define L_ 4096
#define H_ 8
#define D_ 64
#define M_ 128
#define BH_ 16
#define HD_ 512
#define LHD_ (L_*HD_)
#define C_ 64
#define T_ 64
#define RATIO 0.08838834764831845f
#define EPS 1e-3f

#define REC_CS 8320                    // shorts per cs record: 64*128 KVt + 128 ks
#define REC_F  8192                    // shorts per Qf record: 64*128
#define QF_OFF 8519680                 // shorts: 16*64*8320
#define N2_OFF 16908288                // shorts: QF_OFF + 16*64*8192 (f32 region)
#define RS_OFF 25296896                // shorts (f32 region)
#define P_OFF  25427968                // shorts; P bf16 [m][d]

// XOR-swizzles (bank-conflict-free, keep 8-short groups contiguous):
#define SWZ64(r,c)  ((r)*64  + ((c) ^ (((r)&7)*8)))
#define SWZ128(r,c) ((r)*128 + ((c) ^ (((r)&15)*8)))

typedef __attribute__((ext_vector_type(8))) short bf16x8;
typedef __attribute__((ext_vector_type(4))) short bf16x4;
typedef __attribute__((ext_vector_type(4))) float f32x4;

__device__ __forceinline__ short f2bf(float f) {
  union { float f; unsigned u; } x; x.f = f;
  unsigned r = (x.u + 0x7fffu + ((x.u >> 16) & 1u)) >> 16;
  return (short)r;
}
__device__ __forceinline__ float bf2f(short s) {
  union { unsigned u; float f; } x; x.u = ((unsigned)(unsigned short)s) << 16;
  return x.f;
}
__device__ __forceinline__ bf16x8 cvt8(float4 a, float4 b) {
  union { bf16x8 v; short s[8]; } u;
  u.s[0]=f2bf(a.x); u.s[1]=f2bf(a.y); u.s[2]=f2bf(a.z); u.s[3]=f2bf(a.w);
  u.s[4]=f2bf(b.x); u.s[5]=f2bf(b.y); u.s[6]=f2bf(b.z); u.s[7]=f2bf(b.w);
  return u.v;
}
#define MFMA(a,b,c) __builtin_amdgcn_mfma_f32_16x16x32_bf16((a),(b),(c),0,0,0)

// ---------------- k0: P -> bf16 once ----------------------------------------
__global__ __launch_bounds__(256) void k0(
    const float* __restrict__ P, unsigned short* __restrict__ ws)
{
  const int i = (blockIdx.x*256 + threadIdx.x)*4;   // 8 blocks * 256 * 4 = 8192
  float4 p4 = *(const float4*)(P + i);
  union { bf16x4 v; short s[4]; } u;
  u.s[0]=f2bf(p4.x); u.s[1]=f2bf(p4.y); u.s[2]=f2bf(p4.z); u.s[3]=f2bf(p4.w);
  *(bf16x4*)(ws + P_OFF + i) = u.v;
}

// ---------------- k1: all intra-chunk work (40KB LDS, 4 blocks/CU) ----------
__global__ __launch_bounds__(256) void k1(
    const float* __restrict__ qq, const float* __restrict__ kk,
    const float* __restrict__ vv, unsigned short* __restrict__ ws)
{
  __shared__ short Vt[64*64];        // [d][t], SWZ64 (8KB)
  __shared__ short Kft[128*64];      // [m][t], SWZ64 (16KB); rows 0-63 -> Sm later
  __shared__ short KfTM[64*128];     // [t][m], SWZ128 (16KB)

  const int tid = threadIdx.x, bid = blockIdx.x;
  const int bh = bid >> 6, c = bid & 63;
  const int b = bh >> 3, h = bh & 7;
  const int lane = tid & 63, w = tid >> 6, quad = lane >> 4, l15 = lane & 15;
  const size_t gbase = (size_t)b*LHD_ + (size_t)h*D_;
  const int t0 = c*T_;
  const int trow = 16*w + l15;
  const unsigned short* Pb = ws + P_OFF;

  // issue q/k row loads first (latency overlaps Vt staging)
  const float* qrow = qq + gbase + (size_t)(t0 + trow)*HD_;
  const float* krow = kk + gbase + (size_t)(t0 + trow)*HD_;
  float4 q4a = *(const float4*)(qrow + quad*8);
  float4 q4b = *(const float4*)(qrow + quad*8 + 4);
  float4 q4c = *(const float4*)(qrow + 32 + quad*8);
  float4 q4d = *(const float4*)(qrow + 32 + quad*8 + 4);
  float4 k4a = *(const float4*)(krow + quad*8);
  float4 k4b = *(const float4*)(krow + quad*8 + 4);
  float4 k4c = *(const float4*)(krow + 32 + quad*8);
  float4 k4d = *(const float4*)(krow + 32 + quad*8 + 4);

  // stage Vt[d][t] (transpose, swizzled)
  for (int fi = tid; fi < 64*16; fi += 256) {
    int t = fi >> 4, d4 = (fi & 15)*4;
    float4 v4 = *(const float4*)(vv + gbase + (size_t)(t0+t)*HD_ + d4);
    Vt[SWZ64(d4+0, t)] = f2bf(v4.x);
    Vt[SWZ64(d4+1, t)] = f2bf(v4.y);
    Vt[SWZ64(d4+2, t)] = f2bf(v4.z);
    Vt[SWZ64(d4+3, t)] = f2bf(v4.w);
  }

  bf16x8 bq0 = cvt8(q4a, q4b), bq1 = cvt8(q4c, q4d);
  bf16x8 bk0 = cvt8(k4a, k4b), bk1 = cvt8(k4c, k4d);

  unsigned short* qfb = ws + QF_OFF + (size_t)(bh*C_+c)*REC_F;
  unsigned short* csb = ws + (size_t)(bh*C_+c)*REC_CS;

  // features, swapped operands: D[m][t] -> lane holds t=trow, m=16ct+4quad+reg
  bf16x4 qreg[8];
  #pragma unroll
  for (int ct = 0; ct < 8; ++ct) {
    bf16x8 ap0 = *(const bf16x8*)(Pb + (ct*16 + l15)*64 + quad*8);
    bf16x8 ap1 = *(const bf16x8*)(Pb + (ct*16 + l15)*64 + 32 + quad*8);
    f32x4 qa = {0.f,0.f,0.f,0.f}, ka = {0.f,0.f,0.f,0.f};
    qa = MFMA(ap0,bq0,qa); qa = MFMA(ap1,bq1,qa);
    ka = MFMA(ap0,bk0,ka); ka = MFMA(ap1,bk1,ka);
    union { bf16x4 v; short s[4]; } pq, pk;
    #pragma unroll
    for (int reg = 0; reg < 4; ++reg) {
      int m = 16*ct + 4*quad + reg;
      short qv = f2bf(fmaxf(qa[reg]*RATIO, 0.f) + EPS);
      short kv = f2bf(fmaxf(ka[reg]*RATIO, 0.f) + EPS);
      pq.s[reg] = qv; pk.s[reg] = kv;
      Kft[SWZ64(m, trow)] = kv;
    }
    qreg[ct] = pq.v;
    *(bf16x4*)(qfb + trow*128 + 16*ct + 4*quad) = pq.v;
    *(bf16x4*)&KfTM[SWZ128(trow, 16*ct + 4*quad)] = pk.v;
  }

  // Qf A-frags via in-wave shuffles (no LDS):
  // dest lane (q,l15) wants Qf[trow][32ks2+8q .. +7]:
  //   lo half from lane (2(q&1))*16+l15, reg qreg[2ks2+(q>>1)]
  //   hi half from lane (2(q&1)+1)*16+l15, same reg
  bf16x8 qfr[4];
  {
    const int src_lo = (2*(quad & 1))*16 + l15;
    #pragma unroll
    for (int ks2 = 0; ks2 < 4; ++ks2) {
      union { bf16x4 v; long long l; } a0, a1;
      a0.v = qreg[2*ks2]; a1.v = qreg[2*ks2+1];
      long long loA = __shfl(a0.l, src_lo, 64);
      long long hiA = __shfl(a0.l, src_lo + 16, 64);
      long long loB = __shfl(a1.l, src_lo, 64);
      long long hiB = __shfl(a1.l, src_lo + 16, 64);
      union { bf16x8 v8; long long l[2]; } r;
      r.l[0] = (quad < 2) ? loA : loB;
      r.l[1] = (quad < 2) ? hiA : hiB;
      qfr[ks2] = r.v8;
    }
  }
  __syncthreads();  // sync1: Vt, Kft, KfTM complete

  // ks[m] = sum_t Kf[t][m] (row-sum of Kft)
  if (tid < 128) {
    float s = 0.f;
    #pragma unroll
    for (int i = 0; i < 8; ++i) {
      bf16x8 r = *(const bf16x8*)&Kft[SWZ64(tid, 8*i)];
      #pragma unroll
      for (int j = 0; j < 8; ++j) s += bf2f(r[j]);
    }
    csb[64*128 + tid] = (unsigned short)f2bf(s);
  }

  // KV^T: cs[d][m] = sum_t Kf[t][m] V[t][d]; D[m][d], packed 8B stores
  {
    bf16x8 av0 = *(const bf16x8*)&Vt[SWZ64(trow, 8*quad)];
    bf16x8 av1 = *(const bf16x8*)&Vt[SWZ64(trow, 32 + 8*quad)];
    #pragma unroll
    for (int mt = 0; mt < 8; ++mt) {
      bf16x8 b0 = *(const bf16x8*)&Kft[SWZ64(16*mt + l15, 8*quad)];
      bf16x8 b1 = *(const bf16x8*)&Kft[SWZ64(16*mt + l15, 32 + 8*quad)];
      f32x4 acc = {0.f,0.f,0.f,0.f};
      acc = MFMA(b0, av0, acc);
      acc = MFMA(b1, av1, acc);
      union { bf16x4 v; short s[4]; } pc;
      #pragma unroll
      for (int reg = 0; reg < 4; ++reg) pc.s[reg] = f2bf(acc[reg]);
      *(bf16x4*)(csb + trow*128 + 16*mt + 4*quad) = pc.v;
    }
  }

  // S = mask(Qf Kf^T): D[t][j], A=Qf shuffled regs, B=KfTM rows
  f32x4 sacc[4];
  #pragma unroll
  for (int jt = 0; jt < 4; ++jt) { f32x4 z = {0.f,0.f,0.f,0.f}; sacc[jt] = z; }
  #pragma unroll
  for (int ks2 = 0; ks2 < 4; ++ks2) {
    #pragma unroll
    for (int jt = 0; jt < 4; ++jt) {
      bf16x8 bb = *(const bf16x8*)&KfTM[SWZ128(16*jt + l15, 32*ks2 + 8*quad)];
      sacc[jt] = MFMA(qfr[ks2], bb, sacc[jt]);
    }
  }
  __syncthreads();  // sync2: all Kft/KfTM reads done -> Kft rows 0-63 reusable

  // mask + rowsum + Sm (reuse Kft; same-wave rows only -> no further barrier)
  short* Sm = Kft;
  float rs[4] = {0.f,0.f,0.f,0.f};
  #pragma unroll
  for (int jt = 0; jt < 4; ++jt)
    #pragma unroll
    for (int reg = 0; reg < 4; ++reg) {
      int row = 16*w + 4*quad + reg;
      int j = l15 + 16*jt;
      float val = (j <= row) ? sacc[jt][reg] : 0.f;
      rs[reg] += val;
      Sm[SWZ64(row, j)] = f2bf(val);
    }
  #pragma unroll
  for (int reg = 0; reg < 4; ++reg) {
    rs[reg] += __shfl_xor(rs[reg], 1);
    rs[reg] += __shfl_xor(rs[reg], 2);
    rs[reg] += __shfl_xor(rs[reg], 4);
    rs[reg] += __shfl_xor(rs[reg], 8);
  }
  float* rsg = (float*)(ws + RS_OFF);
  if (l15 < 4) {
    float v = (l15==0) ? rs[0] : (l15==1) ? rs[1] : (l15==2) ? rs[2] : rs[3];
    rsg[bh*L_ + t0 + 16*w + 4*quad + l15] = v;
  }

  // num2[t][d] = S V as D[d][t]: A=Vt rows d, B=Sm rows t (same-wave)
  float* n2 = (float*)(ws + N2_OFF);
  f32x4 nacc[4];
  #pragma unroll
  for (int ct = 0; ct < 4; ++ct) { f32x4 z = {0.f,0.f,0.f,0.f}; nacc[ct] = z; }
  #pragma unroll
  for (int kss = 0; kss < 2; ++kss) {
    bf16x8 sb = *(const bf16x8*)&Sm[SWZ64(trow, 32*kss + 8*quad)];
    #pragma unroll
    for (int ct = 0; ct < 4; ++ct) {
      bf16x8 a = *(const bf16x8*)&Vt[SWZ64(16*ct + l15, 32*kss + 8*quad)];
      nacc[ct] = MFMA(a, sb, nacc[ct]);
    }
  }
  const int tg = t0 + trow;
  #pragma unroll
  for (int ct = 0; ct < 4; ++ct) {
    float4 o;
    o.x = nacc[ct][0]; o.y = nacc[ct][1]; o.z = nacc[ct][2]; o.w = nacc[ct][3];
    *(float4*)(n2 + gbase + (size_t)tg*HD_ + 16*ct + 4*quad) = o;
  }
}

// ---------------- k2: bf16 exclusive prefix, 520x64, bf16x4 prefetch --------
__global__ __launch_bounds__(64) void k2(unsigned short* __restrict__ ws)
{
  const int gid = blockIdx.x*64 + threadIdx.x;   // 520*64 = 33280 = 16*2080
  const int bh = gid / 2080, e = (gid % 2080)*4;
  unsigned short* base = ws + (size_t)bh*C_*REC_CS + e;
  bf16x4 v[64];
  #pragma unroll
  for (int c2 = 0; c2 < 64; ++c2) v[c2] = *(const bf16x4*)(base + (size_t)c2*REC_CS);
  float run[4] = {0.f,0.f,0.f,0.f};
  #pragma unroll
  for (int c2 = 0; c2 < 64; ++c2) {
    union { bf16x4 v; short s[4]; } wv;
    #pragma unroll
    for (int j = 0; j < 4; ++j) { wv.s[j] = f2bf(run[j]); run[j] += bf2f(v[c2][j]); }
    *(bf16x4*)(base + (size_t)c2*REC_CS) = wv.v;
  }
}

// ---------------- k3: num1 + combine; cs LDS-staged once --------------------
__global__ __launch_bounds__(256) void k3(
    const unsigned short* __restrict__ ws, float* __restrict__ out)
{
  __shared__ short csL[64*128];     // [d][m], SWZ128
  __shared__ float ks_lds[128];

  const int tid = threadIdx.x, bid = blockIdx.x;
  const int bh = bid >> 6, c = bid & 63;
  const int b = bh >> 3, h = bh & 7;
  const int lane = tid & 63, w = tid >> 6, quad = lane >> 4, l15 = lane & 15;
  const size_t gbase = (size_t)b*LHD_ + (size_t)h*D_;
  const int t0 = c*T_;
  const unsigned short* csb = ws + (size_t)(bh*C_+c)*REC_CS;
  const unsigned short* qfb = ws + QF_OFF + (size_t)(bh*C_+c)*REC_F;
  const float* n2 = (const float*)(ws + N2_OFF);
  const float* rsg = (const float*)(ws + RS_OFF);
  const int trow = 16*w + l15;
  const int tg = t0 + trow;

  // stage cs[d][m] (coalesced 16B reads), ks as f32
  for (int i = tid; i < 1024; i += 256) {
    int row = i >> 4, cb = (i & 15)*8;
    *(bf16x8*)&csL[SWZ128(row, cb)] = *(const bf16x8*)(csb + i*8);
  }
  if (tid < 128) ks_lds[tid] = bf2f((short)csb[64*128 + tid]);

  // hoisted global loads: n2, rs, Qf frags (all workspace -> L2/L3-hot)
  float4 nv[4];
  #pragma unroll
  for (int ct = 0; ct < 4; ++ct)
    nv[ct] = *(const float4*)(n2 + gbase + (size_t)tg*HD_ + 16*ct + 4*quad);
  float rsv = rsg[bh*L_ + tg];
  bf16x8 qfB[4];
  #pragma unroll
  for (int ks2 = 0; ks2 < 4; ++ks2)
    qfB[ks2] = *(const bf16x8*)(qfb + trow*128 + ks2*32 + quad*8);

  __syncthreads();

  // den1 = Qf . ks_prefix (per-lane partial over 32 m, reduce across quads)
  float dp = 0.f;
  #pragma unroll
  for (int ks2 = 0; ks2 < 4; ++ks2)
    #pragma unroll
    for (int j = 0; j < 8; ++j) dp += bf2f(qfB[ks2][j]) * ks_lds[ks2*32 + quad*8 + j];
  dp += __shfl_xor(dp, 16);
  dp += __shfl_xor(dp, 32);
  float inv = 1.f / (dp + rsv);

  // num1 = Qf * KVpre as D[d][t]: A=csL rows d, B=Qf rows t
  f32x4 nacc[4];
  #pragma unroll
  for (int ct = 0; ct < 4; ++ct) { f32x4 z = {0.f,0.f,0.f,0.f}; nacc[ct] = z; }
  #pragma unroll
  for (int ks2 = 0; ks2 < 4; ++ks2) {
    #pragma unroll
    for (int ct = 0; ct < 4; ++ct) {
      bf16x8 a = *(const bf16x8*)&csL[SWZ128(16*ct + l15, 32*ks2 + 8*quad)];
      nacc[ct] = MFMA(a, qfB[ks2], nacc[ct]);
    }
  }
  #pragma unroll
  for (int ct = 0; ct < 4; ++ct) {
    float4 o;
    o.x = (nacc[ct][0] + nv[ct].x) * inv;
    o.y = (nacc[ct][1] + nv[ct].y) * inv;
    o.z = (nacc[ct][2] + nv[ct].z) * inv;
    o.w = (nacc[ct][3] + nv[ct].w) * inv;
    *(float4*)(out + gbase + (size_t)tg*HD_ + 16*ct + 4*quad) = o;
  }
}

extern "C" void kernel_launch(void* const* d_in, const int* in_sizes, int n_in,
                              void* d_out, int out_size, void* d_ws, size_t ws_size,
                              hipStream_t stream) {
  const float* q = (const float*)d_in[0];
  const float* k = (const float*)d_in[1];
  const float* v = (const float*)d_in[2];
  const float* P = (const float*)d_in[3];
  float* out = (float*)d_out;
  unsigned short* ws = (unsigned short*)d_ws;  // needs ~50.9 MB

  k0<<<dim3(8),      dim3(256), 0, stream>>>(P, ws);
  k1<<<dim3(BH_*C_), dim3(256), 0, stream>>>(q, k, v, ws);
  k2<<<dim3(520),    dim3(64),  0, stream>>>(ws);
  k3<<<dim3(BH_*C_), dim3(256), 0, stream>>>(ws, out);
}